// Round 1
// baseline (682.750 us; speedup 1.0000x reference)
//
#include <hip/hip_runtime.h>
#include <hip/hip_bf16.h>
#include <math.h>

#define B_ 4
#define S_ 1024
#define T_ (B_ * S_)      // 4096 tokens
#define D_ 1024
#define H_ 4096
#define E_ 8
#define K_ 2
#define A_ (T_ * K_)      // 8192 assignments
#define NTM_ 40           // max m-tiles at BM=256: 32 + 7 = 39 <= 40

typedef __bf16 bf16x8_t __attribute__((ext_vector_type(8)));
typedef float f32x4_t __attribute__((ext_vector_type(4)));
typedef unsigned short u16x8_t __attribute__((ext_vector_type(8)));

__device__ inline unsigned short f2bf(float f) {
    __hip_bfloat16 h = __float2bfloat16(f);
    return *reinterpret_cast<unsigned short*>(&h);
}

// async global->LDS, 16B per lane. LDS dest = wave-uniform base + lane*16.
__device__ __forceinline__ void gl2lds16(const unsigned short* g, unsigned short* l) {
    auto* gp = reinterpret_cast<const __attribute__((address_space(1))) unsigned int*>(
        reinterpret_cast<uintptr_t>(g));
    auto* lp = reinterpret_cast<__attribute__((address_space(3))) unsigned int*>(
        reinterpret_cast<uintptr_t>(l));
    __builtin_amdgcn_global_load_lds(gp, lp, 16, 0, 0);
}

// Padded control block:
//   counts_pad : int   ctrl + 0    + e*128
//   probs_pad  : float ctrl + 1024 + e*128
//   cursors_pad: int   ctrl + 2048 + e*128
//   offsets    : int[9]  ctrl + 3072
//   tile_e     : int[40] ctrl + 3200
//   tile_m     : int[40] ctrl + 3584
//   n_tiles    : int     ctrl + 3968

// ---------------- router: 16 tokens/block, LDS-aggregated stats -----------
__global__ void router_kernel(const float* __restrict__ x, const float* __restrict__ rw,
                              int* __restrict__ tok_e, float* __restrict__ tok_w,
                              int* __restrict__ counts_pad, float* __restrict__ probs_pad) {
    __shared__ float s_probs[E_];
    __shared__ int s_counts[E_];
    const int tid = threadIdx.x;
    if (tid < E_) { s_probs[tid] = 0.f; s_counts[tid] = 0; }
    __syncthreads();
    const int wave = tid >> 6;
    const int lane = tid & 63;

    float wprob[E_];
    int wcount[E_];
#pragma unroll
    for (int e = 0; e < E_; ++e) { wprob[e] = 0.f; wcount[e] = 0; }

    for (int tt = 0; tt < 4; ++tt) {
        const int token = blockIdx.x * 16 + wave * 4 + tt;
        const float* xr = x + (long)token * D_;
        float acc[E_];
#pragma unroll
        for (int e = 0; e < E_; ++e) acc[e] = 0.f;
        for (int i = 0; i < D_ / 64; ++i) {
            int d = i * 64 + lane;
            float xv = xr[d];
            const float* w = rw + (long)d * E_;
#pragma unroll
            for (int e = 0; e < E_; ++e) acc[e] += xv * w[e];
        }
#pragma unroll
        for (int e = 0; e < E_; ++e) {
            for (int off = 32; off > 0; off >>= 1)
                acc[e] += __shfl_down(acc[e], off);
        }
        if (lane == 0) {
            float m = acc[0];
            for (int e = 1; e < E_; ++e) m = fmaxf(m, acc[e]);
            float p[E_], s = 0.f;
            for (int e = 0; e < E_; ++e) { p[e] = expf(acc[e] - m); s += p[e]; }
            float inv = 1.f / s;
            for (int e = 0; e < E_; ++e) { p[e] *= inv; wprob[e] += p[e]; }
            int i0 = 0;
            for (int e = 1; e < E_; ++e) if (p[e] > p[i0]) i0 = e;
            int i1 = (i0 == 0) ? 1 : 0;
            for (int e = 0; e < E_; ++e) if (e != i0 && p[e] > p[i1]) i1 = e;
            float w0 = p[i0], w1 = p[i1];
            float inv2 = 1.f / (w0 + w1 + 1e-8f);
            tok_e[token * 2] = i0;
            tok_e[token * 2 + 1] = i1;
            tok_w[token * 2] = w0 * inv2;
            tok_w[token * 2 + 1] = w1 * inv2;
            wcount[i0]++; wcount[i1]++;
        }
    }
    if (lane == 0) {
#pragma unroll
        for (int e = 0; e < E_; ++e) {
            atomicAdd(&s_probs[e], wprob[e]);
            if (wcount[e]) atomicAdd(&s_counts[e], wcount[e]);
        }
    }
    __syncthreads();
    if (tid < E_) {
        atomicAdd(&probs_pad[tid * 32], s_probs[tid]);
        if (s_counts[tid]) atomicAdd(&counts_pad[tid * 32], s_counts[tid]);
    }
}

// ------------- offsets + aux loss + compact tile table (BM=256) -----------
__global__ void offsets_aux_kernel(const int* __restrict__ counts_pad,
                                   const float* __restrict__ probs_pad,
                                   int* __restrict__ offsets,
                                   int* __restrict__ tile_e, int* __restrict__ tile_m,
                                   int* __restrict__ n_tiles, float* __restrict__ aux_out) {
    if (threadIdx.x == 0 && blockIdx.x == 0) {
        int run = 0, t = 0;
        for (int e = 0; e < E_; ++e) {
            int c = counts_pad[e * 32];
            offsets[e] = run;
            for (int m0 = 0; m0 < c; m0 += 256) {
                tile_e[t] = e; tile_m[t] = m0; ++t;
            }
            run += c;
        }
        offsets[E_] = run;
        *n_tiles = t;
        float aux = 0.f;
        for (int e = 0; e < E_; ++e)
            aux += (probs_pad[e * 32] / (float)T_) * ((float)counts_pad[e * 32] / (float)A_);
        *aux_out = (float)E_ * aux;
    }
}

// ---------------- scatter: wave-aggregated ranking, padded cursors --------
__global__ void scatter_kernel(const int* __restrict__ tok_e, const float* __restrict__ tok_w,
                               const int* __restrict__ offsets, int* __restrict__ cursors_pad,
                               int* __restrict__ perm_token, float* __restrict__ perm_weight,
                               int* __restrict__ inv_pos) {
    int i = blockIdx.x * blockDim.x + threadIdx.x;
    int lane = threadIdx.x & 63;
    int e = tok_e[i];
    float w = tok_w[i];
    unsigned long long bal[E_];
#pragma unroll
    for (int q = 0; q < E_; ++q) bal[q] = __ballot(e == q);
    unsigned long long below = (1ull << lane) - 1ull;
    int rank = __popcll(bal[e] & below);
    int base = 0;
    if (lane < E_) {
        int c = __popcll(bal[lane]);
        if (c) base = atomicAdd(&cursors_pad[lane * 32], c);
    }
    int mybase = __shfl(base, e);
    int pos = offsets[e] + mybase + rank;
    perm_token[pos] = i >> 1;
    perm_weight[pos] = w;
    inv_pos[i] = pos;
}

// ---------------- fp32 -> bf16 cast of x ----------------------------------
__global__ void cast_x_kernel(const float* __restrict__ x, unsigned short* __restrict__ xb) {
    long i = (long)blockIdx.x * blockDim.x + threadIdx.x;
    float4 v = reinterpret_cast<const float4*>(x)[i];
    unsigned long long packed = (unsigned long long)f2bf(v.x)
        | ((unsigned long long)f2bf(v.y) << 16)
        | ((unsigned long long)f2bf(v.z) << 32)
        | ((unsigned long long)f2bf(v.w) << 48);
    reinterpret_cast<unsigned long long*>(xb)[i] = packed;
}

// -------- fp32 [R][C] -> bf16 [C][R] per expert, vectorized both sides ----
// 64x64 tile per block, 256 threads. float4 reads, ushort8 (16B) writes.
__global__ void transpose_cast_kernel(const float* __restrict__ in, unsigned short* __restrict__ out,
                                      int R, int C) {
    __shared__ float tile[64][65];
    const long e = blockIdx.z;
    const float* in_e = in + e * (long)R * C;
    unsigned short* out_e = out + e * (long)R * C;
    const int c0 = blockIdx.x * 64;
    const int r0 = blockIdx.y * 64;
    const int tid = threadIdx.x;
    const int c4 = (tid & 15) * 4;
    const int rb = tid >> 4;
#pragma unroll
    for (int i = 0; i < 4; ++i) {
        const int r = rb + i * 16;
        const float4 v = *reinterpret_cast<const float4*>(&in_e[(long)(r0 + r) * C + c0 + c4]);
        tile[r][c4] = v.x; tile[r][c4 + 1] = v.y; tile[r][c4 + 2] = v.z; tile[r][c4 + 3] = v.w;
    }
    __syncthreads();
    const int rs = (tid & 7) * 8;
    const int cb = tid >> 3;
#pragma unroll
    for (int i = 0; i < 2; ++i) {
        const int c = cb + i * 32;
        u16x8_t p;
#pragma unroll
        for (int j = 0; j < 8; ++j) p[j] = f2bf(tile[rs + j][c]);
        *reinterpret_cast<u16x8_t*>(&out_e[(long)(c0 + c) * R + r0 + rs]) = p;
    }
}

// ------------- grouped GEMM: 256x128 tile, BK=64, 8 waves, 3-stage LDS ----
// Pipeline: while computing K-tile t (buf t%3), stage tile t+2 (buf (t+2)%3);
// tile t+1 sits resident. Inter-tile sync = per-wave s_waitcnt vmcnt(6) +
// raw s_barrier (all waves' loads for the next tile are landed after the
// barrier; the prefetch queue is never drained to 0 until the tail).
// LDS XOR swizzle: slot (r,c) holds global k-chunk c^(r&7) (pre-swizzled
// global source address, linear LDS dest, swizzled ds_read offset).
template <int PHASE, int NSPLIT>
__launch_bounds__(512, 2)
__global__ void moe_gemm_kernel(const unsigned short* __restrict__ A_src,
                                const unsigned short* __restrict__ B_src,  // [E][N][K] bf16
                                const float* __restrict__ bias,            // [E][N]
                                const int* __restrict__ offsets,
                                const int* __restrict__ tile_e, const int* __restrict__ tile_m,
                                const int* __restrict__ p_ntiles,
                                const int* __restrict__ perm_token,
                                const float* __restrict__ perm_weight,
                                unsigned short* __restrict__ h_buf,
                                float* __restrict__ y_perm) {
    constexpr int Ksz  = (PHASE == 1) ? D_ : H_;           // full A-row length
    constexpr int Kloc = (PHASE == 1) ? D_ : (H_ / NSPLIT); // K handled per block
    constexpr int Nsz  = (PHASE == 1) ? H_ : D_;
    constexpr int NT   = Kloc / 64;                         // K-tiles
    constexpr int NTN  = Nsz / 128;

    // bijective XCD-chunked swizzle; mt fastest within a chunk (B-panel reuse)
    const int nwg = gridDim.x;
    const int id = blockIdx.x;
    const int q = nwg >> 3, r8 = nwg & 7;
    const int xcd = id & 7, sub = id >> 3;
    const int wg = (xcd < r8 ? xcd * (q + 1) : r8 * (q + 1) + (xcd - r8) * q) + sub;
    const int mt = wg % NTM_;
    if (mt >= *p_ntiles) return;
    const int rest = wg / NTM_;
    const int nt = rest % NTN;
    const int kh = rest / NTN;                              // split-K index
    const int e = tile_e[mt];
    const int m0 = tile_m[mt];
    const int off_e = offsets[e];
    const int n_e = offsets[e + 1] - off_e;
    const int n0 = nt * 128;
    const long k_base = (long)kh * Kloc;

    __shared__ __attribute__((aligned(16))) unsigned short lds_a[3 * 256 * 64]; // 96 KB
    __shared__ __attribute__((aligned(16))) unsigned short lds_b[3 * 128 * 64]; // 48 KB

    const int tid = threadIdx.x;
    const int lane = tid & 63;
    const int wave = tid >> 6;
    const int wr = wave >> 1;          // 0..3  (64-row strip)
    const int wc = wave & 1;           // 0..1  (64-col strip)
    const int lrow = lane & 15;
    const int kg = lane >> 4;

    // staging: A tile 256x64 = 2048 16B-chunks (4/thread); B 128x64 (2/thread)
    const unsigned short* gA[4];
    const unsigned short* gB[2];
    int dstA[4], dstB[2];
#pragma unroll
    for (int j = 0; j < 4; ++j) {
        const int chunk = j * 512 + tid;
        const int rr = chunk >> 3;
        const int ch = tid & 7;
        const int m_loc = m0 + rr;
        const int m_cl = (m_loc < n_e) ? m_loc : (n_e - 1);
        const int pos = off_e + m_cl;
        long arow;
        if (PHASE == 1) arow = (long)perm_token[pos] * Ksz;
        else            arow = (long)pos * Ksz;
        gA[j] = A_src + arow + k_base + ((ch ^ (rr & 7)) * 8);
        dstA[j] = (j * 512 + wave * 64) * 8;
    }
#pragma unroll
    for (int j = 0; j < 2; ++j) {
        const int chunk = j * 512 + tid;
        const int rr = chunk >> 3;
        const int ch = tid & 7;
        gB[j] = B_src + (long)e * Nsz * Ksz + (long)(n0 + rr) * Ksz + k_base + ((ch ^ (rr & 7)) * 8);
        dstB[j] = (j * 512 + wave * 64) * 8;
    }

    // ds_read offsets (ushort units), per kf half and per fragment
    int aoff[2][4], boff[2][4];
#pragma unroll
    for (int kf = 0; kf < 2; ++kf)
#pragma unroll
        for (int i = 0; i < 4; ++i) {
            const int r = wr * 64 + i * 16 + lrow;
            aoff[kf][i] = r * 64 + (((kf * 4 + kg) ^ (r & 7)) * 8);
            const int c = wc * 64 + i * 16 + lrow;
            boff[kf][i] = c * 64 + (((kf * 4 + kg) ^ (c & 7)) * 8);
        }

    f32x4_t acc[4][4];
#pragma unroll
    for (int i = 0; i < 4; ++i)
#pragma unroll
        for (int j = 0; j < 4; ++j) acc[i][j] = (f32x4_t){0.f, 0.f, 0.f, 0.f};

    // prologue: stage tiles 0 and 1 (12 loads/thread in flight)
#pragma unroll
    for (int tt = 0; tt < 2; ++tt) {
        gl2lds16(gA[0] + tt * 64, lds_a + tt * 16384 + dstA[0]);
        gl2lds16(gA[1] + tt * 64, lds_a + tt * 16384 + dstA[1]);
        gl2lds16(gB[0] + tt * 64, lds_b + tt * 8192 + dstB[0]);
        gl2lds16(gA[2] + tt * 64, lds_a + tt * 16384 + dstA[2]);
        gl2lds16(gA[3] + tt * 64, lds_a + tt * 16384 + dstA[3]);
        gl2lds16(gB[1] + tt * 64, lds_b + tt * 8192 + dstB[1]);
    }
    asm volatile("s_waitcnt vmcnt(6)" ::: "memory");   // tile 0 landed; tile 1 in flight
    __builtin_amdgcn_s_barrier();

    for (int t = 0; t < NT; ++t) {
        const int s = t % 3;
        const int s2 = (t + 2) % 3;
        const unsigned short* la = lds_a + s * 16384;
        const unsigned short* lb = lds_b + s * 8192;
        const bool pf = (t + 2 < NT);

        // ---- phase kf=0: reads + stage-issue, then barrier'd MFMA cluster --
        bf16x8_t a0[4], b0[4];
#pragma unroll
        for (int i = 0; i < 4; ++i) a0[i] = *reinterpret_cast<const bf16x8_t*>(la + aoff[0][i]);
#pragma unroll
        for (int i = 0; i < 4; ++i) b0[i] = *reinterpret_cast<const bf16x8_t*>(lb + boff[0][i]);
        if (pf) {
            gl2lds16(gA[0] + (t + 2) * 64, lds_a + s2 * 16384 + dstA[0]);
            gl2lds16(gA[1] + (t + 2) * 64, lds_a + s2 * 16384 + dstA[1]);
            gl2lds16(gB[0] + (t + 2) * 64, lds_b + s2 * 8192 + dstB[0]);
        }
        __builtin_amdgcn_s_barrier();
        asm volatile("s_waitcnt lgkmcnt(0)" ::: "memory");
        __builtin_amdgcn_sched_barrier(0);
        __builtin_amdgcn_s_setprio(1);
#pragma unroll
        for (int i = 0; i < 4; ++i)
#pragma unroll
            for (int j = 0; j < 4; ++j)
                acc[i][j] = __builtin_amdgcn_mfma_f32_16x16x32_bf16(a0[i], b0[j], acc[i][j], 0, 0, 0);
        __builtin_amdgcn_s_setprio(0);
        __builtin_amdgcn_s_barrier();

        // ---- phase kf=1 ---------------------------------------------------
        bf16x8_t a1[4], b1[4];
#pragma unroll
        for (int i = 0; i < 4; ++i) a1[i] = *reinterpret_cast<const bf16x8_t*>(la + aoff[1][i]);
#pragma unroll
        for (int i = 0; i < 4; ++i) b1[i] = *reinterpret_cast<const bf16x8_t*>(lb + boff[1][i]);
        if (pf) {
            gl2lds16(gA[2] + (t + 2) * 64, lds_a + s2 * 16384 + dstA[2]);
            gl2lds16(gA[3] + (t + 2) * 64, lds_a + s2 * 16384 + dstA[3]);
            gl2lds16(gB[1] + (t + 2) * 64, lds_b + s2 * 8192 + dstB[1]);
        }
        __builtin_amdgcn_s_barrier();
        asm volatile("s_waitcnt lgkmcnt(0)" ::: "memory");
        __builtin_amdgcn_sched_barrier(0);
        __builtin_amdgcn_s_setprio(1);
#pragma unroll
        for (int i = 0; i < 4; ++i)
#pragma unroll
            for (int j = 0; j < 4; ++j)
                acc[i][j] = __builtin_amdgcn_mfma_f32_16x16x32_bf16(a1[i], b1[j], acc[i][j], 0, 0, 0);
        __builtin_amdgcn_s_setprio(0);
        // inter-tile wait: tile t+1 must be landed; tolerate t+2's 6 loads
        if (t + 1 < NT) {
            if (t + 2 < NT) asm volatile("s_waitcnt vmcnt(6)" ::: "memory");
            else            asm volatile("s_waitcnt vmcnt(0)" ::: "memory");
        }
        __builtin_amdgcn_s_barrier();
    }

    // epilogue
    const float* bias_e = bias + (long)e * Nsz;
    if (PHASE == 1) {
#pragma unroll
        for (int i = 0; i < 4; ++i) {
#pragma unroll
            for (int rq = 0; rq < 4; ++rq) {
                const int row_loc = wr * 64 + i * 16 + kg * 4 + rq;
                const int m_loc = m0 + row_loc;
                if (m_loc >= n_e) continue;
                const int pos = off_e + m_loc;
#pragma unroll
                for (int j = 0; j < 4; ++j) {
                    const int n = n0 + wc * 64 + j * 16 + lrow;
                    float v = acc[i][j][rq] + bias_e[n];
                    v = 0.5f * v * (1.0f + erff(v * 0.70710678118654752440f));
                    h_buf[(long)pos * Nsz + n] = f2bf(v);
                }
            }
        }
    } else {
        float* yp = y_perm + (long)kh * ((long)A_ * D_);
#pragma unroll
        for (int i = 0; i < 4; ++i) {
#pragma unroll
            for (int rq = 0; rq < 4; ++rq) {
                const int row_loc = wr * 64 + i * 16 + kg * 4 + rq;
                const int m_loc = m0 + row_loc;
                if (m_loc >= n_e) continue;
                const int pos = off_e + m_loc;
                const float wgt = perm_weight[pos];
#pragma unroll
                for (int j = 0; j < 4; ++j) {
                    const int n = n0 + wc * 64 + j * 16 + lrow;
                    float v = acc[i][j][rq] + ((kh == 0) ? bias_e[n] : 0.f);
                    yp[(long)pos * Nsz + n] = v * wgt;
                }
            }
        }
    }
}

// ---------------- combine: out[t] = sum of (split) partials ---------------
__global__ void combine_kernel(const float* __restrict__ y_perm, const int* __restrict__ inv_pos,
                               float* __restrict__ out, int splitk) {
    int t = blockIdx.x;
    int d4 = threadIdx.x;                 // 0..255, float4 index (D_/4 = 256)
    int p0 = inv_pos[t * 2];
    int p1 = inv_pos[t * 2 + 1];
    const float4* y0 = reinterpret_cast<const float4*>(y_perm);
    float4 a = y0[(long)p0 * (D_ / 4) + d4];
    float4 b = y0[(long)p1 * (D_ / 4) + d4];
    float4 o = {a.x + b.x, a.y + b.y, a.z + b.z, a.w + b.w};
    if (splitk) {
        const float4* y1 = reinterpret_cast<const float4*>(y_perm + (long)A_ * D_);
        float4 c = y1[(long)p0 * (D_ / 4) + d4];
        float4 d = y1[(long)p1 * (D_ / 4) + d4];
        o.x += c.x + d.x; o.y += c.y + d.y; o.z += c.z + d.z; o.w += c.w + d.w;
    }
    reinterpret_cast<float4*>(out + (long)t * D_)[d4] = o;
}

extern "C" void kernel_launch(void* const* d_in, const int* in_sizes, int n_in,
                              void* d_out, int out_size, void* d_ws, size_t ws_size,
                              hipStream_t stream) {
    const float* x        = (const float*)d_in[0];
    const float* router_W = (const float*)d_in[1];
    const float* W_in     = (const float*)d_in[2];
    const float* b_in     = (const float*)d_in[3];
    const float* W_out    = (const float*)d_in[4];
    const float* b_out    = (const float*)d_in[5];
    float* out = (float*)d_out;

    char* ws = (char*)d_ws;
    size_t off = 0;
    auto alloc = [&](size_t bytes) -> void* {
        void* p = ws + off;
        off += (bytes + 255) & ~(size_t)255;
        return p;
    };

    // split-K for phase 2 only if workspace can hold the second partial buffer
    const int splitk = (ws_size >= (size_t)290 * 1024 * 1024) ? 1 : 0;

    char* ctrl = (char*)alloc(4096);
    int* counts_pad   = (int*)ctrl;                 // e*128 B apart
    float* probs_pad  = (float*)(ctrl + 1024);
    int* cursors_pad  = (int*)(ctrl + 2048);
    int* offsets      = (int*)(ctrl + 3072);
    int* tile_e       = (int*)(ctrl + 3200);
    int* tile_m       = (int*)(ctrl + 3584);
    int* n_tiles      = (int*)(ctrl + 3968);
    int* tok_e         = (int*)alloc((size_t)A_ * 4);
    float* tok_w       = (float*)alloc((size_t)A_ * 4);
    int* perm_token    = (int*)alloc((size_t)A_ * 4);
    float* perm_weight = (float*)alloc((size_t)A_ * 4);
    int* inv_pos       = (int*)alloc((size_t)A_ * 4);
    unsigned short* x_bf    = (unsigned short*)alloc((size_t)T_ * D_ * 2);
    unsigned short* w_in_t  = (unsigned short*)alloc((size_t)E_ * D_ * H_ * 2);
    unsigned short* w_out_t = (unsigned short*)alloc((size_t)E_ * D_ * H_ * 2);
    unsigned short* h_buf   = (unsigned short*)alloc((size_t)A_ * H_ * 2);
    float* y_perm           = (float*)alloc((size_t)(1 + splitk) * A_ * D_ * 4);

    hipMemsetAsync(ctrl, 0, 4096, stream);

    cast_x_kernel<<<(T_ * D_ / 4) / 256, 256, 0, stream>>>(x, x_bf);
    transpose_cast_kernel<<<dim3(H_ / 64, D_ / 64, E_), 256, 0, stream>>>(W_in, w_in_t, D_, H_);
    transpose_cast_kernel<<<dim3(D_ / 64, H_ / 64, E_), 256, 0, stream>>>(W_out, w_out_t, H_, D_);
    router_kernel<<<T_ / 16, 256, 0, stream>>>(x, router_W, tok_e, tok_w, counts_pad, probs_pad);
    offsets_aux_kernel<<<1, 64, 0, stream>>>(counts_pad, probs_pad, offsets,
                                             tile_e, tile_m, n_tiles, out + (out_size - 1));
    scatter_kernel<<<A_ / 256, 256, 0, stream>>>(tok_e, tok_w, offsets, cursors_pad,
                                                 perm_token, perm_weight, inv_pos);

    moe_gemm_kernel<1, 1><<<NTM_ * (H_ / 128), 512, 0, stream>>>(
        x_bf, w_in_t, b_in, offsets, tile_e, tile_m, n_tiles,
        perm_token, perm_weight, h_buf, y_perm);
    if (splitk) {
        moe_gemm_kernel<2, 2><<<NTM_ * (D_ / 128) * 2, 512, 0, stream>>>(
            h_buf, w_out_t, b_out, offsets, tile_e, tile_m, n_tiles,
            perm_token, perm_weight, h_buf, y_perm);
    } else {
        moe_gemm_kernel<2, 1><<<NTM_ * (D_ / 128), 512, 0, stream>>>(
            h_buf, w_out_t, b_out, offsets, tile_e, tile_m, n_tiles,
            perm_token, perm_weight, h_buf, y_perm);
    }
    combine_kernel<<<T_, 256, 0, stream>>>(y_perm, inv_pos, out, splitk);
}

// Round 2
// 678.284 us; speedup vs baseline: 1.0066x; 1.0066x over previous
//
#include <hip/hip_runtime.h>
#include <hip/hip_bf16.h>
#include <math.h>

#define B_ 4
#define S_ 1024
#define T_ (B_ * S_)      // 4096 tokens
#define D_ 1024
#define H_ 4096
#define E_ 8
#define K_ 2
#define A_ (T_ * K_)      // 8192 assignments
#define NTM_ 40           // max m-tiles at BM=256: 32 + 7 = 39 <= 40

typedef __bf16 bf16x8_t __attribute__((ext_vector_type(8)));
typedef float f32x4_t __attribute__((ext_vector_type(4)));
typedef unsigned short u16x8_t __attribute__((ext_vector_type(8)));

__device__ inline unsigned short f2bf(float f) {
    __hip_bfloat16 h = __float2bfloat16(f);
    return *reinterpret_cast<unsigned short*>(&h);
}

// async global->LDS, 16B per lane. LDS dest = wave-uniform base + lane*16.
__device__ __forceinline__ void gl2lds16(const unsigned short* g, unsigned short* l) {
    auto* gp = reinterpret_cast<const __attribute__((address_space(1))) unsigned int*>(
        reinterpret_cast<uintptr_t>(g));
    auto* lp = reinterpret_cast<__attribute__((address_space(3))) unsigned int*>(
        reinterpret_cast<uintptr_t>(l));
    __builtin_amdgcn_global_load_lds(gp, lp, 16, 0, 0);
}

// ---------------- router: 16 tokens/block, LDS-aggregated stats -----------
__global__ void router_kernel(const float* __restrict__ x, const float* __restrict__ rw,
                              int* __restrict__ tok_e, float* __restrict__ tok_w,
                              int* __restrict__ counts_pad, float* __restrict__ probs_pad) {
    __shared__ float s_probs[E_];
    __shared__ int s_counts[E_];
    const int tid = threadIdx.x;
    if (tid < E_) { s_probs[tid] = 0.f; s_counts[tid] = 0; }
    __syncthreads();
    const int wave = tid >> 6;
    const int lane = tid & 63;

    float wprob[E_];
    int wcount[E_];
#pragma unroll
    for (int e = 0; e < E_; ++e) { wprob[e] = 0.f; wcount[e] = 0; }

    for (int tt = 0; tt < 4; ++tt) {
        const int token = blockIdx.x * 16 + wave * 4 + tt;
        const float* xr = x + (long)token * D_;
        float acc[E_];
#pragma unroll
        for (int e = 0; e < E_; ++e) acc[e] = 0.f;
        for (int i = 0; i < D_ / 64; ++i) {
            int d = i * 64 + lane;
            float xv = xr[d];
            const float* w = rw + (long)d * E_;
#pragma unroll
            for (int e = 0; e < E_; ++e) acc[e] += xv * w[e];
        }
#pragma unroll
        for (int e = 0; e < E_; ++e) {
            for (int off = 32; off > 0; off >>= 1)
                acc[e] += __shfl_down(acc[e], off);
        }
        if (lane == 0) {
            float m = acc[0];
            for (int e = 1; e < E_; ++e) m = fmaxf(m, acc[e]);
            float p[E_], s = 0.f;
            for (int e = 0; e < E_; ++e) { p[e] = expf(acc[e] - m); s += p[e]; }
            float inv = 1.f / s;
            for (int e = 0; e < E_; ++e) { p[e] *= inv; wprob[e] += p[e]; }
            int i0 = 0;
            for (int e = 1; e < E_; ++e) if (p[e] > p[i0]) i0 = e;
            int i1 = (i0 == 0) ? 1 : 0;
            for (int e = 0; e < E_; ++e) if (e != i0 && p[e] > p[i1]) i1 = e;
            float w0 = p[i0], w1 = p[i1];
            float inv2 = 1.f / (w0 + w1 + 1e-8f);
            tok_e[token * 2] = i0;
            tok_e[token * 2 + 1] = i1;
            tok_w[token * 2] = w0 * inv2;
            tok_w[token * 2 + 1] = w1 * inv2;
            wcount[i0]++; wcount[i1]++;
        }
    }
    if (lane == 0) {
#pragma unroll
        for (int e = 0; e < E_; ++e) {
            atomicAdd(&s_probs[e], wprob[e]);
            if (wcount[e]) atomicAdd(&s_counts[e], wcount[e]);
        }
    }
    __syncthreads();
    if (tid < E_) {
        atomicAdd(&probs_pad[tid * 32], s_probs[tid]);
        if (s_counts[tid]) atomicAdd(&counts_pad[tid * 32], s_counts[tid]);
    }
}

// ------------- offsets + aux loss + compact tile table (BM=256) -----------
__global__ void offsets_aux_kernel(const int* __restrict__ counts_pad,
                                   const float* __restrict__ probs_pad,
                                   int* __restrict__ offsets,
                                   int* __restrict__ tile_e, int* __restrict__ tile_m,
                                   int* __restrict__ n_tiles, float* __restrict__ aux_out) {
    if (threadIdx.x == 0 && blockIdx.x == 0) {
        int run = 0, t = 0;
        for (int e = 0; e < E_; ++e) {
            int c = counts_pad[e * 32];
            offsets[e] = run;
            for (int m0 = 0; m0 < c; m0 += 256) {
                tile_e[t] = e; tile_m[t] = m0; ++t;
            }
            run += c;
        }
        offsets[E_] = run;
        *n_tiles = t;
        float aux = 0.f;
        for (int e = 0; e < E_; ++e)
            aux += (probs_pad[e * 32] / (float)T_) * ((float)counts_pad[e * 32] / (float)A_);
        *aux_out = (float)E_ * aux;
    }
}

// ---------------- scatter: wave-aggregated ranking, padded cursors --------
__global__ void scatter_kernel(const int* __restrict__ tok_e, const float* __restrict__ tok_w,
                               const int* __restrict__ offsets, int* __restrict__ cursors_pad,
                               int* __restrict__ perm_token, float* __restrict__ perm_weight,
                               int* __restrict__ inv_pos) {
    int i = blockIdx.x * blockDim.x + threadIdx.x;
    int lane = threadIdx.x & 63;
    int e = tok_e[i];
    float w = tok_w[i];
    unsigned long long bal[E_];
#pragma unroll
    for (int q = 0; q < E_; ++q) bal[q] = __ballot(e == q);
    unsigned long long below = (1ull << lane) - 1ull;
    int rank = __popcll(bal[e] & below);
    int base = 0;
    if (lane < E_) {
        int c = __popcll(bal[lane]);
        if (c) base = atomicAdd(&cursors_pad[lane * 32], c);
    }
    int mybase = __shfl(base, e);
    int pos = offsets[e] + mybase + rank;
    perm_token[pos] = i >> 1;
    perm_weight[pos] = w;
    inv_pos[i] = pos;
}

// ---------------- fp32 -> bf16 cast of x ----------------------------------
__global__ void cast_x_kernel(const float* __restrict__ x, unsigned short* __restrict__ xb) {
    long i = (long)blockIdx.x * blockDim.x + threadIdx.x;
    float4 v = reinterpret_cast<const float4*>(x)[i];
    unsigned long long packed = (unsigned long long)f2bf(v.x)
        | ((unsigned long long)f2bf(v.y) << 16)
        | ((unsigned long long)f2bf(v.z) << 32)
        | ((unsigned long long)f2bf(v.w) << 48);
    reinterpret_cast<unsigned long long*>(xb)[i] = packed;
}

// -------- fp32 [R][C] -> bf16 [C][R] per expert, vectorized both sides ----
__global__ void transpose_cast_kernel(const float* __restrict__ in, unsigned short* __restrict__ out,
                                      int R, int C) {
    __shared__ float tile[64][65];
    const long e = blockIdx.z;
    const float* in_e = in + e * (long)R * C;
    unsigned short* out_e = out + e * (long)R * C;
    const int c0 = blockIdx.x * 64;
    const int r0 = blockIdx.y * 64;
    const int tid = threadIdx.x;
    const int c4 = (tid & 15) * 4;
    const int rb = tid >> 4;
#pragma unroll
    for (int i = 0; i < 4; ++i) {
        const int r = rb + i * 16;
        const float4 v = *reinterpret_cast<const float4*>(&in_e[(long)(r0 + r) * C + c0 + c4]);
        tile[r][c4] = v.x; tile[r][c4 + 1] = v.y; tile[r][c4 + 2] = v.z; tile[r][c4 + 3] = v.w;
    }
    __syncthreads();
    const int rs = (tid & 7) * 8;
    const int cb = tid >> 3;
#pragma unroll
    for (int i = 0; i < 2; ++i) {
        const int c = cb + i * 32;
        u16x8_t p;
#pragma unroll
        for (int j = 0; j < 8; ++j) p[j] = f2bf(tile[rs + j][c]);
        *reinterpret_cast<u16x8_t*>(&out_e[(long)(c0 + c) * R + r0 + rs]) = p;
    }
}

// ---- grouped GEMM: 256xBN tile, BK=32, 8 waves (per-wave 128x64), --------
// ---- 3 K-tile LDS buffers, 1 barrier/tile, counted vmcnt ----------------
// Per K-tile, 2 phases; phase p: {ds_read A-half (+B in ph0), issue 1-2
// gl2lds16 of tile t+2, lgkmcnt(0), setprio(1), MH*4 MFMA, setprio(0)}.
// No intra-tile barrier (reads of same buffer are hazard-free) -> waves
// desync so one wave's ds_reads overlap another's MFMA cluster. Tile
// boundary: s_waitcnt vmcnt(SI) (= t+2's own loads outstanding; never 0
// mid-loop) + s_barrier. LDS swizzle: 64B rows, chunk c stored from global
// chunk c^((row>>1)&3) -> 2-way bank access on ds_read_b128 (free).
template <int PHASE, int BN_, int NSPLIT>
__launch_bounds__(512, 2)
__global__ void moe_gemm_kernel(const unsigned short* __restrict__ A_src,
                                const unsigned short* __restrict__ B_src,  // [E][N][K] bf16
                                const float* __restrict__ bias,            // [E][N]
                                const int* __restrict__ offsets,
                                const int* __restrict__ tile_e, const int* __restrict__ tile_m,
                                const int* __restrict__ p_ntiles,
                                const int* __restrict__ perm_token,
                                const float* __restrict__ perm_weight,
                                unsigned short* __restrict__ h_buf,
                                float* __restrict__ y_perm) {
    constexpr int Ksz  = (PHASE == 1) ? D_ : H_;    // full A-row length
    constexpr int Kloc = Ksz / NSPLIT;              // K per block
    constexpr int Nsz  = (PHASE == 1) ? H_ : D_;
    constexpr int NT   = Kloc / 32;                 // K-tiles
    constexpr int NTN  = Nsz / BN_;
    constexpr int WN   = BN_ / 64;                  // waves along N (4 or 2)
    constexpr int WM   = 8 / WN;                    // waves along M (2 or 4)
    constexpr int MROWS = 256 / WM;                 // rows per wave (128 or 64)
    constexpr int MF   = MROWS / 16;                // m-frags (8 or 4)
    constexpr int MH   = MF / 2;                    // m-frags per phase
    constexpr int AI   = 2;                         // A stage instrs/wave/tile
    constexpr int BI   = BN_ / 128;                 // B stage instrs/wave/tile
    constexpr int SI   = AI + BI;
    constexpr int ABUF = 256 * 32;                  // shorts per A buffer
    constexpr int BBUF = BN_ * 32;                  // shorts per B buffer

    // bijective XCD-chunked swizzle; mt fastest (B panel L2-resident per XCD)
    const int nwg = gridDim.x;
    const int id = blockIdx.x;
    const int q = nwg >> 3, r8 = nwg & 7;
    const int xcd = id & 7, sub = id >> 3;
    const int wg = (xcd < r8 ? xcd * (q + 1) : r8 * (q + 1) + (xcd - r8) * q) + sub;
    const int mt = wg % NTM_;
    if (mt >= *p_ntiles) return;
    const int rest = wg / NTM_;
    const int nt = rest % NTN;
    const int kh = rest / NTN;                      // split-K index
    const int e = tile_e[mt];
    const int m0 = tile_m[mt];
    const int off_e = offsets[e];
    const int n_e = offsets[e + 1] - off_e;
    const int n0 = nt * BN_;
    const long k_base = (long)kh * Kloc;

    __shared__ __attribute__((aligned(16))) unsigned short lds_a[3 * ABUF];
    __shared__ __attribute__((aligned(16))) unsigned short lds_b[3 * BBUF];

    const int tid = threadIdx.x;
    const int lane = tid & 63;
    const int wave = tid >> 6;
    const int wr = wave / WN;
    const int wc = wave % WN;
    const int lrow = lane & 15;
    const int kg = lane >> 4;

    // staging: instr j covers rows g*16..g*16+15 (g = wave*AI+j for A),
    // lane: row g*16+(lane>>2), chunk lane&3; source chunk XOR-swizzled.
    const int srow = lane >> 2;                       // row within group
    const int sch  = (lane & 3) ^ ((lane >> 3) & 3);  // swizzled source chunk
    const unsigned short* gA[AI];
    const unsigned short* gB[BI];
#pragma unroll
    for (int j = 0; j < AI; ++j) {
        const int g = wave * AI + j;
        const int m_loc = m0 + g * 16 + srow;
        const int m_cl = (m_loc < n_e) ? m_loc : (n_e - 1);
        const int pos = off_e + m_cl;
        long arow;
        if (PHASE == 1) arow = (long)perm_token[pos] * Ksz;
        else            arow = (long)pos * Ksz;
        gA[j] = A_src + arow + k_base + sch * 8;
    }
#pragma unroll
    for (int j = 0; j < BI; ++j) {
        const int g = wave * BI + j;
        gB[j] = B_src + (long)e * Nsz * Ksz + (long)(n0 + g * 16 + srow) * Ksz + k_base + sch * 8;
    }

    // ds_read bases (shorts): row-major [row][32], chunk = kg ^ ((lrow>>1)&3)
    const int rch = (kg ^ ((lrow >> 1) & 3)) * 8;
    const int abase = (wr * MROWS + lrow) * 32 + rch;
    const int bbase = (wc * 64 + lrow) * 32 + rch;

    f32x4_t acc[MF][4];
#pragma unroll
    for (int i = 0; i < MF; ++i)
#pragma unroll
        for (int j = 0; j < 4; ++j) acc[i][j] = (f32x4_t){0.f, 0.f, 0.f, 0.f};

    // prologue: stage tiles 0,1
#pragma unroll
    for (int tt = 0; tt < 2; ++tt) {
#pragma unroll
        for (int j = 0; j < AI; ++j)
            gl2lds16(gA[j] + tt * 32, lds_a + tt * ABUF + (wave * AI + j) * 512);
#pragma unroll
        for (int j = 0; j < BI; ++j)
            gl2lds16(gB[j] + tt * 32, lds_b + tt * BBUF + (wave * BI + j) * 512);
    }
    if constexpr (SI == 4) asm volatile("s_waitcnt vmcnt(4)" ::: "memory");
    else                   asm volatile("s_waitcnt vmcnt(3)" ::: "memory");
    __builtin_amdgcn_s_barrier();

    int s = 0;
    for (int t = 0; t < NT; ++t) {
        const int s2 = (s + 2 >= 3) ? s - 1 : s + 2;
        const unsigned short* la = lds_a + s * ABUF;
        const unsigned short* lb = lds_b + s * BBUF;
        const bool pf = (t + 2 < NT);

        bf16x8_t b_frag[4];
#pragma unroll
        for (int p = 0; p < 2; ++p) {
            bf16x8_t a_frag[MH];
#pragma unroll
            for (int f = 0; f < MH; ++f)
                a_frag[f] = *reinterpret_cast<const bf16x8_t*>(la + abase + (p * MH + f) * 512);
            if (p == 0) {
#pragma unroll
                for (int j = 0; j < 4; ++j)
                    b_frag[j] = *reinterpret_cast<const bf16x8_t*>(lb + bbase + j * 512);
            }
            if (pf) {
                gl2lds16(gA[p] + (t + 2) * 32, lds_a + s2 * ABUF + (wave * AI + p) * 512);
                if (p < BI)
                    gl2lds16(gB[p] + (t + 2) * 32, lds_b + s2 * BBUF + (wave * BI + p) * 512);
            }
            asm volatile("s_waitcnt lgkmcnt(0)" ::: "memory");
            __builtin_amdgcn_sched_barrier(0);
            __builtin_amdgcn_s_setprio(1);
#pragma unroll
            for (int f = 0; f < MH; ++f)
#pragma unroll
                for (int j = 0; j < 4; ++j)
                    acc[p * MH + f][j] = __builtin_amdgcn_mfma_f32_16x16x32_bf16(
                        a_frag[f], b_frag[j], acc[p * MH + f][j], 0, 0, 0);
            __builtin_amdgcn_s_setprio(0);
        }
        // tile boundary: tile t+1 must be landed; t+2's SI loads may fly
        if (t + 1 < NT) {
            if (pf) {
                if constexpr (SI == 4) asm volatile("s_waitcnt vmcnt(4)" ::: "memory");
                else                   asm volatile("s_waitcnt vmcnt(3)" ::: "memory");
            } else {
                asm volatile("s_waitcnt vmcnt(0)" ::: "memory");
            }
            __builtin_amdgcn_s_barrier();
        }
        s = (s + 1 >= 3) ? 0 : s + 1;
    }

    // epilogue
    const float* bias_e = bias + (long)e * Nsz;
    if (PHASE == 1) {
#pragma unroll
        for (int i = 0; i < MF; ++i) {
#pragma unroll
            for (int rq = 0; rq < 4; ++rq) {
                const int row_loc = wr * MROWS + i * 16 + kg * 4 + rq;
                const int m_loc = m0 + row_loc;
                if (m_loc >= n_e) continue;
                const int pos = off_e + m_loc;
#pragma unroll
                for (int j = 0; j < 4; ++j) {
                    const int n = n0 + wc * 64 + j * 16 + lrow;
                    float v = acc[i][j][rq] + bias_e[n];
                    v = 0.5f * v * (1.0f + erff(v * 0.70710678118654752440f));
                    h_buf[(long)pos * Nsz + n] = f2bf(v);
                }
            }
        }
    } else {
        float* yp = y_perm + (long)kh * ((long)A_ * D_);
#pragma unroll
        for (int i = 0; i < MF; ++i) {
#pragma unroll
            for (int rq = 0; rq < 4; ++rq) {
                const int row_loc = wr * MROWS + i * 16 + kg * 4 + rq;
                const int m_loc = m0 + row_loc;
                if (m_loc >= n_e) continue;
                const int pos = off_e + m_loc;
                const float wgt = perm_weight[pos];
#pragma unroll
                for (int j = 0; j < 4; ++j) {
                    const int n = n0 + wc * 64 + j * 16 + lrow;
                    float v = acc[i][j][rq] + ((kh == 0) ? bias_e[n] : 0.f);
                    yp[(long)pos * Nsz + n] = v * wgt;
                }
            }
        }
    }
}

// ---------------- combine: out[t] = sum of (split) partials ---------------
__global__ void combine_kernel(const float* __restrict__ y_perm, const int* __restrict__ inv_pos,
                               float* __restrict__ out, int splitk) {
    int t = blockIdx.x;
    int d4 = threadIdx.x;                 // 0..255, float4 index (D_/4 = 256)
    int p0 = inv_pos[t * 2];
    int p1 = inv_pos[t * 2 + 1];
    const float4* y0 = reinterpret_cast<const float4*>(y_perm);
    float4 a = y0[(long)p0 * (D_ / 4) + d4];
    float4 b = y0[(long)p1 * (D_ / 4) + d4];
    float4 o = {a.x + b.x, a.y + b.y, a.z + b.z, a.w + b.w};
    if (splitk) {
        const float4* y1 = reinterpret_cast<const float4*>(y_perm + (long)A_ * D_);
        float4 c = y1[(long)p0 * (D_ / 4) + d4];
        float4 d = y1[(long)p1 * (D_ / 4) + d4];
        o.x += c.x + d.x; o.y += c.y + d.y; o.z += c.z + d.z; o.w += c.w + d.w;
    }
    reinterpret_cast<float4*>(out + (long)t * D_)[d4] = o;
}

extern "C" void kernel_launch(void* const* d_in, const int* in_sizes, int n_in,
                              void* d_out, int out_size, void* d_ws, size_t ws_size,
                              hipStream_t stream) {
    const float* x        = (const float*)d_in[0];
    const float* router_W = (const float*)d_in[1];
    const float* W_in     = (const float*)d_in[2];
    const float* b_in     = (const float*)d_in[3];
    const float* W_out    = (const float*)d_in[4];
    const float* b_out    = (const float*)d_in[5];
    float* out = (float*)d_out;

    char* ws = (char*)d_ws;
    size_t off = 0;
    auto alloc = [&](size_t bytes) -> void* {
        void* p = ws + off;
        off += (bytes + 255) & ~(size_t)255;
        return p;
    };

    // split-K for phase 2 only if workspace can hold the second partial buffer
    const int splitk = (ws_size >= (size_t)280 * 1024 * 1024) ? 1 : 0;

    char* ctrl = (char*)alloc(4096);
    int* counts_pad   = (int*)ctrl;                 // e*128 B apart
    float* probs_pad  = (float*)(ctrl + 1024);
    int* cursors_pad  = (int*)(ctrl + 2048);
    int* offsets      = (int*)(ctrl + 3072);
    int* tile_e       = (int*)(ctrl + 3200);
    int* tile_m       = (int*)(ctrl + 3584);
    int* n_tiles      = (int*)(ctrl + 3968);
    int* tok_e         = (int*)alloc((size_t)A_ * 4);
    float* tok_w       = (float*)alloc((size_t)A_ * 4);
    int* perm_token    = (int*)alloc((size_t)A_ * 4);
    float* perm_weight = (float*)alloc((size_t)A_ * 4);
    int* inv_pos       = (int*)alloc((size_t)A_ * 4);
    unsigned short* x_bf    = (unsigned short*)alloc((size_t)T_ * D_ * 2);
    unsigned short* w_in_t  = (unsigned short*)alloc((size_t)E_ * D_ * H_ * 2);
    unsigned short* w_out_t = (unsigned short*)alloc((size_t)E_ * D_ * H_ * 2);
    unsigned short* h_buf   = (unsigned short*)alloc((size_t)A_ * H_ * 2);
    float* y_perm           = (float*)alloc((size_t)(1 + splitk) * A_ * D_ * 4);

    hipMemsetAsync(ctrl, 0, 4096, stream);

    cast_x_kernel<<<(T_ * D_ / 4) / 256, 256, 0, stream>>>(x, x_bf);
    transpose_cast_kernel<<<dim3(H_ / 64, D_ / 64, E_), 256, 0, stream>>>(W_in, w_in_t, D_, H_);
    transpose_cast_kernel<<<dim3(D_ / 64, H_ / 64, E_), 256, 0, stream>>>(W_out, w_out_t, H_, D_);
    router_kernel<<<T_ / 16, 256, 0, stream>>>(x, router_W, tok_e, tok_w, counts_pad, probs_pad);
    offsets_aux_kernel<<<1, 64, 0, stream>>>(counts_pad, probs_pad, offsets,
                                             tile_e, tile_m, n_tiles, out + (out_size - 1));
    scatter_kernel<<<A_ / 256, 256, 0, stream>>>(tok_e, tok_w, offsets, cursors_pad,
                                                 perm_token, perm_weight, inv_pos);

    moe_gemm_kernel<1, 256, 1><<<NTM_ * (H_ / 256), 512, 0, stream>>>(
        x_bf, w_in_t, b_in, offsets, tile_e, tile_m, n_tiles,
        perm_token, perm_weight, h_buf, y_perm);
    if (splitk) {
        moe_gemm_kernel<2, 256, 2><<<NTM_ * (D_ / 256) * 2, 512, 0, stream>>>(
            h_buf, w_out_t, b_out, offsets, tile_e, tile_m, n_tiles,
            perm_token, perm_weight, h_buf, y_perm);
    } else {
        moe_gemm_kernel<2, 128, 1><<<NTM_ * (D_ / 128), 512, 0, stream>>>(
            h_buf, w_out_t, b_out, offsets, tile_e, tile_m, n_tiles,
            perm_token, perm_weight, h_buf, y_perm);
    }
    combine_kernel<<<T_, 256, 0, stream>>>(y_perm, inv_pos, out, splitk);
}